// Round 4
// baseline (703.679 us; speedup 1.0000x reference)
//
#include <hip/hip_runtime.h>

// EvoBinarizedLayer: out[p,b,o] = x@W0 + (1-x)@W1 = x@(W0-W1) + colsum_i(W1)
// x:[32,512,1024] {0,1} fp32; w:[2,32,1024,1024] {0,1} fp32; out fp32. Exact in bf16.
//
// R4: fused DMA pipeline. R1-R3 were all latency-convoy bound on register-coupled
// fp32 global loads (~150-190us vs 64us HBM floor). Here ALL global reads are
// global_load_lds DMA (fire-and-forget, no VGPRs, deep queue): fp32 tiles land in
// LDS untouched; convert/diff/transpose is an LDS->LDS stage; MFMA(k-1) overlaps
// DMA(k) flight. Epilogue via LDS shuffle -> coalesced dwordx4 (kills out-RFO).

namespace {

constexpr int PP = 32;
constexpr int BBATCH = 512;
constexpr int II = 1024;
constexpr int OO = 1024;

typedef __attribute__((ext_vector_type(8))) short bf16x8;
typedef __attribute__((ext_vector_type(4))) float f32x4;

// fp32 -> bf16 truncation: exact for {0,+-1}. Pack (lo,hi) into u32.
__device__ __forceinline__ unsigned pk2(float lo, float hi) {
    return (__float_as_uint(lo) >> 16) | (__float_as_uint(hi) & 0xFFFF0000u);
}

__device__ __forceinline__ void dma16(const float* g, char* l) {
    __builtin_amdgcn_global_load_lds(
        (const __attribute__((address_space(1))) unsigned int*)g,
        (__attribute__((address_space(3))) unsigned int*)l, 16, 0, 0);
}

// LDS map (bytes). K-loop: fp32 landing zones + bf16 operand buffers = 68KB
//  -> 2 blocks/CU (136KB of 160KB).
constexpr int XF   = 0;       // [128 b][32 k] f32 packed, 128B rows  (16KB)
constexpr int W0F  = 16384;   // [32 k][128 o] f32 packed, 512B rows  (16KB)
constexpr int W1F  = 32768;   //                                      (16KB)
constexpr int ABo  = 49152;   // A bf16 [128 b][k], 40-elem (80B) rows (10240B)
constexpr int BBo  = 59392;   // B bf16 [128 o][k], 40-elem rows       (10240B)
constexpr int LDST = 69632;
// Epilogue reuse of the fp32 region (dead after last convert):
constexpr int OUTS = 0;       // [64 rows][132 f32] (528B stride -> conflict-free)
constexpr int CSP  = 36864;   // colsum partials [8][128] f32

__global__ __launch_bounds__(512, 4) void ebl_kernel(const float* __restrict__ x,
                                                     const float* __restrict__ w,
                                                     float* __restrict__ out) {
    __shared__ __align__(16) char smem[LDST];

    const int t  = (int)threadIdx.x;
    const int l  = t & 63;
    const int wv = t >> 6;     // 0..7
    const int wm = wv & 1;     // m-half (64 rows)
    const int wn = wv >> 1;    // n-quarter (32 cols)
    const int lq = l >> 4;
    const int ln = l & 15;

    const int p  = (int)blockIdx.z;
    const int b0 = (int)blockIdx.y * 128;
    const int o0 = (int)blockIdx.x * 128;

    const float* xg  = x + ((size_t)p * BBATCH + b0) * II;
    const float* w0g = w + (size_t)p * II * OO + o0;
    const float* w1g = w + (size_t)(PP + p) * II * OO + o0;

    // ---- per-wave DMA geometry (LDS base wave-uniform; global addr per-lane) ----
    // waves 0,1: x rows (8 instr x 8 rows); waves 2,3: W0 (8 instr x 2 k-rows);
    // waves 4,5: W1; waves 6,7: no DMA.
    const int xrow_l = (l >> 3);        // row within 8-row group
    const int xcol_l = (l & 7) * 4;     // f32 col within 32
    const int wrow_l = (l >> 5);        // k-row within pair
    const int wcol_l = (l & 31) * 4;    // f32 col within 128

    // ---- MFMA fragment offsets (bytes), loop-invariant ----
    int a_off[4], b_off[2];
#pragma unroll
    for (int mt = 0; mt < 4; ++mt)
        a_off[mt] = ABo + (wm * 64 + mt * 16 + ln) * 80 + lq * 16;
#pragma unroll
    for (int nt = 0; nt < 2; ++nt)
        b_off[nt] = BBo + (wn * 32 + nt * 16 + ln) * 80 + lq * 16;

    f32x4 acc[4][2];
#pragma unroll
    for (int mt = 0; mt < 4; ++mt)
#pragma unroll
        for (int nt = 0; nt < 2; ++nt)
            acc[mt][nt] = (f32x4){0.f, 0.f, 0.f, 0.f};

    // B-convert identity (threads 0..255): o-group m (4 cols), k-group kg (4 ks).
    const int cm = t & 31;
    const int kg = (t >> 5) & 7;
    // A-convert identity (threads 256..511): 4 chunks of 16B each.
    const int au = t & 255;

    f32x4 cs = (f32x4){0.f, 0.f, 0.f, 0.f};  // colsum(W1) partial, o = 4cm..+3

    // ---------------- DMA issue for one K-step ----------------
    auto dma_step = [&](int kk) {
        const int kbase = kk * 32;
        if (wv < 2) {
#pragma unroll
            for (int q = 0; q < 8; ++q) {
                const int r0 = wv * 64 + 8 * q;
                dma16(xg + (size_t)(r0 + xrow_l) * II + kbase + xcol_l,
                      smem + XF + r0 * 128);
            }
        } else if (wv < 4) {
#pragma unroll
            for (int q = 0; q < 8; ++q) {
                const int kr0 = (wv - 2) * 16 + 2 * q;
                dma16(w0g + (size_t)(kbase + kr0 + wrow_l) * OO + wcol_l,
                      smem + W0F + kr0 * 512);
            }
        } else if (wv < 6) {
#pragma unroll
            for (int q = 0; q < 8; ++q) {
                const int kr0 = (wv - 4) * 16 + 2 * q;
                dma16(w1g + (size_t)(kbase + kr0 + wrow_l) * OO + wcol_l,
                      smem + W1F + kr0 * 512);
            }
        }
    };

    // ---------------- LDS convert stage ----------------
    auto convert_step = [&]() {
        if (t < 256) {
            // B: diff + transpose. Read W0/W1 [k][o] b128 (4-way conflict, 1.58x),
            // write [o][k] b64. Thread: o=4cm..+3, k=4kg..+3.
            f32x4 d[4];
            f32x4 b1s[4];
#pragma unroll
            for (int j = 0; j < 4; ++j) {
                const int krow = 4 * kg + j;
                f32x4 a = *(const f32x4*)(smem + W0F + krow * 512 + cm * 16);
                f32x4 b = *(const f32x4*)(smem + W1F + krow * 512 + cm * 16);
                d[j] = a - b;
                b1s[j] = b;
            }
            cs += b1s[0]; cs += b1s[1]; cs += b1s[2]; cs += b1s[3];
#pragma unroll
            for (int c = 0; c < 4; ++c) {
                uint2 v = make_uint2(pk2(d[0][c], d[1][c]), pk2(d[2][c], d[3][c]));
                *(uint2*)(smem + BBo + (4 * cm + c) * 80 + 8 * kg) = v;
            }
        } else {
            // A: pass-through convert, fully coalesced LDS reads/writes.
#pragma unroll
            for (int s = 0; s < 4; ++s) {
                const int f = au + 256 * s;       // chunk id 0..1023
                const int row = f >> 3, ch = f & 7;
                f32x4 v = *(const f32x4*)(smem + XF + row * 128 + ch * 16);
                *(uint2*)(smem + ABo + row * 80 + ch * 8) =
                    make_uint2(pk2(v.x, v.y), pk2(v.z, v.w));
            }
        }
    };

    // ---------------- MFMA step (reads bf16 bufs) ----------------
    auto mfma_step = [&]() {
        bf16x8 af[4], bf[2];
#pragma unroll
        for (int mt = 0; mt < 4; ++mt) af[mt] = *(const bf16x8*)(smem + a_off[mt]);
#pragma unroll
        for (int nt = 0; nt < 2; ++nt) bf[nt] = *(const bf16x8*)(smem + b_off[nt]);
#pragma unroll
        for (int mt = 0; mt < 4; ++mt)
#pragma unroll
            for (int nt = 0; nt < 2; ++nt)
                acc[mt][nt] = __builtin_amdgcn_mfma_f32_16x16x32_bf16(
                    af[mt], bf[nt], acc[mt][nt], 0, 0, 0);
    };

    // ---------------- pipeline ----------------
    dma_step(0);
    __syncthreads();          // DMA(0) landed
    convert_step();
    __syncthreads();

    for (int kk = 1; kk < 32; ++kk) {
        dma_step(kk);         // overwrites fp32 zones (convert(kk-1) done)
        mfma_step();          // iter kk-1, overlaps DMA flight
        __syncthreads();      // DMA(kk) landed; bf16 reads drained
        convert_step();       // overwrites bf16 bufs (safe: mfma kk-1 done)
        __syncthreads();
    }
    mfma_step();              // iter 31

    // ---------------- colsum reduce ----------------
    if (t < 256)
        *(f32x4*)(smem + CSP + kg * 512 + cm * 16) = cs;
    __syncthreads();
    f32x4 csr = (f32x4){0.f, 0.f, 0.f, 0.f};
#pragma unroll
    for (int g = 0; g < 8; ++g)
        csr += *(const f32x4*)(smem + CSP + g * 512 + (t & 31) * 16);

    // ---------------- epilogue: stage 64 rows at a time, coalesced stores ----
#pragma unroll
    for (int h = 0; h < 2; ++h) {
        __syncthreads();
        if (wm == h) {
#pragma unroll
            for (int mt = 0; mt < 4; ++mt)
#pragma unroll
                for (int nt = 0; nt < 2; ++nt) {
                    const int col = wn * 32 + nt * 16 + ln;
#pragma unroll
                    for (int r = 0; r < 4; ++r) {
                        const int rl = mt * 16 + lq * 4 + r;   // row local 0..63
                        *(float*)(smem + OUTS + rl * 528 + col * 4) = acc[mt][nt][r];
                    }
                }
        }
        __syncthreads();
#pragma unroll
        for (int s = 0; s < 4; ++s) {
            const int idx = t + 512 * s;        // 16B chunk id 0..2047
            const int rl = idx >> 5, c = idx & 31;
            f32x4 v = *(const f32x4*)(smem + OUTS + rl * 528 + c * 16);
            v += csr;                            // c == t&31 for all s
            *(f32x4*)(out + ((size_t)(p * BBATCH + b0 + 64 * h + rl)) * OO + o0 +
                      4 * c) = v;
        }
    }
}

}  // namespace

extern "C" void kernel_launch(void* const* d_in, const int* in_sizes, int n_in,
                              void* d_out, int out_size, void* d_ws, size_t ws_size,
                              hipStream_t stream) {
    const float* x = (const float*)d_in[0];
    const float* w = (const float*)d_in[1];
    float* out = (float*)d_out;
    // x-fastest: the 4 b-blocks sharing a w o-slice are 8 apart -> same XCD L2.
    dim3 grid(OO / 128, BBATCH / 128, PP);  // 1024 blocks, 2/CU (LDS-capped)
    ebl_kernel<<<grid, dim3(512, 1, 1), 0, stream>>>(x, w, out);
}

// Round 5
// 592.983 us; speedup vs baseline: 1.1867x; 1.1867x over previous
//
#include <hip/hip_runtime.h>

// EvoBinarizedLayer: out[p,b,o] = x@W0 + (1-x)@W1 = x@(W0-W1) + colsum_i(W1)
// x:[32,512,1024] {0,1} fp32; w:[2,32,1024,1024] {0,1} fp32; out fp32. Exact in bf16.
//
// R5: BARRIER-FREE wave-autonomous GEMM. R1-R4 all convoyed on the vmcnt(0)
// the compiler emits at every __syncthreads (m97-structure stall, fatal here
// because this kernel is ~all memory, ~no compute). This kernel has no LDS and
// no barriers: each wave computes a 64x64 tile with fragments loaded straight
// from global (x is k-contiguous = clean A-frags; w via 8-dword k-gathers for
// B-frags, 4x64B rows per instr). 8 waves/block share one o-slice -> identical
// B addresses -> L1 dedup; x's 16x reuse served by L3. Loads pipeline freely
// across K-iterations (partial vmcnt waits only).

namespace {

constexpr int PP = 32;
constexpr int BB = 512;
constexpr int II = 1024;
constexpr int OO = 1024;

typedef __attribute__((ext_vector_type(8))) short bf16x8;
typedef __attribute__((ext_vector_type(4))) float f32x4;

// Pack (lo,hi) fp32 pair -> two bf16 in one u32 by truncation (exact for
// {0,+-1}); v_perm_b32: D = [hi.b3, hi.b2, lo.b3, lo.b2].
__device__ __forceinline__ unsigned pk2(float lo, float hi) {
    return __builtin_amdgcn_perm(__float_as_uint(hi), __float_as_uint(lo),
                                 0x07060302u);
}

union BF8 {
    unsigned u[4];
    bf16x8 v;
};

__global__ __launch_bounds__(512, 2) void ebl_kernel(const float* __restrict__ x,
                                                     const float* __restrict__ w,
                                                     float* __restrict__ out) {
    const int t  = (int)threadIdx.x;
    const int l  = t & 63;
    const int wv = t >> 6;     // 0..7: wave's 64-row m-slice
    const int lq = l >> 4;     // quad
    const int ln = l & 15;

    const int p  = (int)blockIdx.y;
    const int o0 = (int)blockIdx.x * 64;
    const int m0 = wv * 64;

    // A: frag element j = x[p][m0+mt*16+ln][kk+8*lq+j]  (k-contiguous)
    const float* xa = x + ((size_t)p * BB + m0 + ln) * II + 8 * lq;
    // B: frag element j = dW[kk+8*lq+j][o0+nt*16+ln], dW = W0-W1 (k-gather)
    const float* wb0 = w + (size_t)p * II * OO + (size_t)(8 * lq) * OO + o0 + ln;
    const float* wb1 = wb0 + (size_t)PP * II * OO;

    f32x4 acc[4][4];
#pragma unroll
    for (int mt = 0; mt < 4; ++mt)
#pragma unroll
        for (int nt = 0; nt < 4; ++nt)
            acc[mt][nt] = (f32x4){0.f, 0.f, 0.f, 0.f};

    float cs[4] = {0.f, 0.f, 0.f, 0.f};  // colsum(W1) partial (this lane's k's)

#pragma unroll 2
    for (int kk = 0; kk < II; kk += 32) {
        // ---- A fragments: 2 dwordx4 + 4 v_perm each ----
        BF8 af[4];
#pragma unroll
        for (int mt = 0; mt < 4; ++mt) {
            const float* ap = xa + (size_t)(mt * 16) * II + kk;
            f32x4 lo = *(const f32x4*)ap;
            f32x4 hi = *(const f32x4*)(ap + 4);
            af[mt].u[0] = pk2(lo.x, lo.y);
            af[mt].u[1] = pk2(lo.z, lo.w);
            af[mt].u[2] = pk2(hi.x, hi.y);
            af[mt].u[3] = pk2(hi.z, hi.w);
        }

        // ---- B fragments: 16-dword k-gather, diff, colsum, pack, 4 MFMA ----
#pragma unroll
        for (int nt = 0; nt < 4; ++nt) {
            const float* b0p = wb0 + (size_t)kk * OO + nt * 16;
            const float* b1p = wb1 + (size_t)kk * OO + nt * 16;
            float q0[8], q1[8];
#pragma unroll
            for (int j = 0; j < 8; ++j) q0[j] = b0p[(size_t)j * OO];
#pragma unroll
            for (int j = 0; j < 8; ++j) q1[j] = b1p[(size_t)j * OO];

            float d[8];
#pragma unroll
            for (int j = 0; j < 8; ++j) {
                d[j] = q0[j] - q1[j];
                cs[nt] += q1[j];
            }
            BF8 bf;
            bf.u[0] = pk2(d[0], d[1]);
            bf.u[1] = pk2(d[2], d[3]);
            bf.u[2] = pk2(d[4], d[5]);
            bf.u[3] = pk2(d[6], d[7]);
#pragma unroll
            for (int mt = 0; mt < 4; ++mt)
                acc[mt][nt] = __builtin_amdgcn_mfma_f32_16x16x32_bf16(
                    af[mt].v, bf.v, acc[mt][nt], 0, 0, 0);
        }
    }

    // ---- colsum: quads hold disjoint k-subsets; butterfly over lanes 16,32.
    // After this every lane has full colsum for o-col = o0 + nt*16 + ln. ----
#pragma unroll
    for (int nt = 0; nt < 4; ++nt) {
        cs[nt] += __shfl_xor(cs[nt], 16);
        cs[nt] += __shfl_xor(cs[nt], 32);
    }

    // ---- epilogue: C/D layout col=lane&15, row=quad*4+reg (m89/m91) ----
    float* op = out + ((size_t)p * BB + m0) * OO + o0;
#pragma unroll
    for (int mt = 0; mt < 4; ++mt)
#pragma unroll
        for (int nt = 0; nt < 4; ++nt) {
            const int col = nt * 16 + ln;
#pragma unroll
            for (int r = 0; r < 4; ++r) {
                const int row = mt * 16 + lq * 4 + r;
                op[(size_t)row * OO + col] = acc[mt][nt][r] + cs[nt];
            }
        }
}

}  // namespace

extern "C" void kernel_launch(void* const* d_in, const int* in_sizes, int n_in,
                              void* d_out, int out_size, void* d_ws, size_t ws_size,
                              hipStream_t stream) {
    const float* x = (const float*)d_in[0];
    const float* w = (const float*)d_in[1];
    float* out = (float*)d_out;
    // block = 8 waves x (64 rows each) = all 512 b-rows of one 64-o slice:
    // B read once per block, deduped in L1 across the 8 waves.
    // o-fastest: 16 consecutive blocks share p -> 2 blocks/XCD share x in L2.
    dim3 grid(OO / 64, PP, 1);  // (16, 32) = 512 blocks
    ebl_kernel<<<grid, dim3(512, 1, 1), 0, stream>>>(x, w, out);
}